// Round 5
// baseline (130.065 us; speedup 1.0000x reference)
//
#include <hip/hip_runtime.h>
#include <hip/hip_bf16.h>

typedef __attribute__((ext_vector_type(8))) short short8;   // 8 bf16 (4 VGPRs)
typedef __attribute__((ext_vector_type(4))) float f32x4;
typedef unsigned int uint;
typedef __attribute__((ext_vector_type(4))) uint uint4v;    // align 16 -> dwordx4/b128

#define AS1 __attribute__((address_space(1)))
#define AS3 __attribute__((address_space(3)))

// ws: Rp4 [0,1MB) | Qp4 [1MB,1.25MB) | xph [1.25MB, +34.1MB)
#define QB_OFF  (1u << 20)
#define XPH_OFF (1310720u)
// xph byte addr: n*1115136 + row*16896 + col*256 + c*2   (row,col in 0..65, c in 0..127)
// Rp4: [s 0..63][cu 0..3][col 0..255]*16B ; holds R[col][k=s*32+cu*8+e]
//      (k-order: g=k>>7 window, c=k&127; f=c*16+g)
// Qp4: [ks 0..7][col 0..511][cu 0..3]*16B ; Q[col][ks*32+cu*8+e]

__device__ __forceinline__ uint bf16r(float f) {
    uint u = __float_as_uint(f);
    u += 0x7FFFu + ((u >> 16) & 1u);
    return u >> 16;
}
__device__ __forceinline__ uint pk2(float lo, float hi) {
    return bf16r(lo) | (bf16r(hi) << 16);
}

// ---------------- prep: NHWC-padded bf16 x, [cu][col] R slabs, Q K-slabs (unchanged, proven) ----------------
__global__ __launch_bounds__(256) void prep_kernel(
    const float* __restrict__ x, const float* __restrict__ Q, const float* __restrict__ R,
    char* __restrict__ Rp4, char* __restrict__ Qp4, char* __restrict__ xph)
{
    const int bid = blockIdx.x, tid = threadIdx.x;
    if (bid < 2048) {                       // transpose: n = bid>>6, h = bid&63
        __shared__ float xt[128 * 65];
        const int n = bid >> 6, h = bid & 63;
        {   // read x[n][c][h][w] coalesced, stage to LDS
            const int c = tid >> 1, half = tid & 1;
            const float4* src = (const float4*)(x + (((size_t)(n * 128 + c) * 64 + h) * 64 + half * 32));
            #pragma unroll
            for (int q = 0; q < 8; ++q) {
                float4 v = src[q];
                float* d = &xt[c * 65 + half * 32 + q * 4];
                d[0] = v.x; d[1] = v.y; d[2] = v.z; d[3] = v.w;
            }
        }
        __syncthreads();
        {   // write xph[n][h+1][w+1][c] (32 channels per thread)
            const int w = tid >> 2, cq = tid & 3;
            uint pw[16];
            #pragma unroll
            for (int m = 0; m < 16; ++m)
                pw[m] = pk2(xt[(cq * 32 + 2 * m) * 65 + w], xt[(cq * 32 + 2 * m + 1) * 65 + w]);
            char* dst = xph + (size_t)n * 1115136 + (size_t)(h + 1) * 16896 + (w + 1) * 256 + cq * 64;
            #pragma unroll
            for (int i = 0; i < 4; ++i) {
                uint4v q4 = { pw[4 * i], pw[4 * i + 1], pw[4 * i + 2], pw[4 * i + 3] };
                *(uint4v*)(dst + i * 16) = q4;
            }
        }
        if (tid < 32) {                      // col borders 0 and 65
            int side = tid >> 4, e = tid & 15;
            uint4v z = {0, 0, 0, 0};
            *(uint4v*)(xph + (size_t)n * 1115136 + (size_t)(h + 1) * 16896 + side * 65 * 256 + e * 16) = z;
        }
        if (h == 0) {                        // row borders 0 and 65
            uint4v z = {0, 0, 0, 0};
            #pragma unroll
            for (int it = 0; it < 9; ++it) {
                int idx = tid + it * 256;
                if (idx < 2112) {
                    int rr = (idx >= 1056) ? 65 : 0;
                    int jj = idx - (rr ? 1056 : 0);
                    int col = jj >> 4, e = jj & 15;
                    *(uint4v*)(xph + (size_t)n * 1115136 + (size_t)rr * 16896 + col * 256 + e * 16) = z;
                }
            }
        }
    } else if (bid < 2304) {                // R -> Rp4[s][cu][col] (linear dst)
        int g = (bid - 2048) * 256 + tid;   // 0..65535
        int s = g >> 10, rem = g & 1023;
        int cu = rem >> 8, col = rem & 255;
        // k = s*32 + cu*8 + e ; g_win = s>>2 ; c = (s&3)*32 + cu*8 + e ; f = c*16 + g_win
        const float* src = R + (size_t)col * 2048 + (((s & 3) * 32 + cu * 8) * 16 + (s >> 2));
        uint pw[4];
        #pragma unroll
        for (int m = 0; m < 4; ++m)
            pw[m] = pk2(src[(2 * m) * 16], src[(2 * m + 1) * 16]);
        uint4v q4 = { pw[0], pw[1], pw[2], pw[3] };
        *(uint4v*)(Rp4 + (size_t)g * 16) = q4;
    } else {                                 // Q -> Qp4[ks][col][cu] (linear dst)
        int g = (bid - 2304) * 256 + tid;   // 0..16383
        int ks = g >> 11, p = g & 2047;
        int col = p >> 2, cu = p & 3;
        const float4* s = (const float4*)(Q + (size_t)col * 256 + ks * 32 + cu * 8);
        float4 a = s[0], b = s[1];
        uint4v q4 = { pk2(a.x, a.y), pk2(a.z, a.w), pk2(b.x, b.y), pk2(b.z, b.w) };
        *(uint4v*)(Qp4 + (size_t)ks * 32768 + p * 16) = q4;
    }
}

// ---------------- fused: BM=64 x BN=256, 256 thr / 4 waves, ZERO-LDS gemm1 ----------------
// Mechanism under test: remove ALL gemm1 synchronization. A (X) and B (R) stream
// global -> registers per wave, double-buffered; compiler inserts per-wave s_waitcnt.
// No LDS staging, no barriers in gemm1 -> resident waves/blocks fully self-paced
// (R0's B-in-regs, the best-measured element, extended to both operands).
// One __syncthreads() total (pos<->rank transpose via 32KB ttile).
// gemm2: 2 mf-half passes (acc 64 VGPR), Q per-wave global b128, results stored
// DIRECTLY to global (dwordx4; lanes of an lr-group cover 128B runs) - no ep LDS.
// LDS 32KB -> blocks/CU capped by waves: ~150 VGPR @ launch_bounds(256,3) -> 12 waves/CU.
__global__ __launch_bounds__(256, 3) void fused_kernel(
    const char* __restrict__ xph, const char* __restrict__ Rp4,
    const char* __restrict__ Qp4, float* __restrict__ out)
{
    extern __shared__ __align__(16) char lds[];

    const int blk = blockIdx.x;
    const int b = (blk & 7) * 64 + (blk >> 3);  // XCD-contiguous swizzle (512%8==0)
    const int n = b >> 4, vt = b & 15;          // block covers ov rows {2vt, 2vt+1} x 32 patch cols
    const int tid = threadIdx.x;
    const int wave = tid >> 6, lane = tid & 63;
    const int lr = lane & 15, kg = lane >> 4;
    const int wn = wave;                        // gemm1 rank-col group; gemm2 (si=wn>>1, ochalf=wn&1)

    // X: af[mf] lane addr = xbase + U(mf) + i*16896 + j*256 + (s&3)*64 + lr*512 + kg*16
    //    (m = mf*16+lr ; rh=m>>5 -> U rows ; cl=m&31 -> lr*512 (+8192 for odd mf))
    const char* xbase = xph + (size_t)n * 1115136 + (size_t)(4 * vt) * 16896;
    const int xv0 = lr * 512 + kg * 16;
    // B: bf[nf] lane addr = Rp4 + s*16384 + kg*4096 + (wn*64 + nf*16 + lr)*16
    const int bv0 = kg * 4096 + (wn * 64 + lr) * 16;

    f32x4 acc[4][4];
    #pragma unroll
    for (int i = 0; i < 4; ++i)
        #pragma unroll
        for (int j = 0; j < 4; ++j) acc[i][j] = (f32x4)0.f;

    short8 afA[4], bfA[4], afB[4], bfB[4];

#define LOADA(dst_, s_) { \
        const char* xp_ = xbase + ((s_) >> 4) * 16896 + (((s_) >> 2) & 3) * 256 + ((s_) & 3) * 64 + xv0; \
        dst_[0] = *(const short8*)(xp_);             \
        dst_[1] = *(const short8*)(xp_ + 8192);      \
        dst_[2] = *(const short8*)(xp_ + 33792);     \
        dst_[3] = *(const short8*)(xp_ + 41984); }
#define LOADB(dst_, s_) { \
        const char* rp_ = Rp4 + (size_t)(s_) * 16384 + bv0; \
        _Pragma("unroll") for (int nf = 0; nf < 4; ++nf) \
            dst_[nf] = *(const short8*)(rp_ + nf * 256); }
#define MFMA16(af_, bf_) { \
        __builtin_amdgcn_s_setprio(1); \
        _Pragma("unroll") for (int nf = 0; nf < 4; ++nf) \
            _Pragma("unroll") for (int mf = 0; mf < 4; ++mf) \
                acc[mf][nf] = __builtin_amdgcn_mfma_f32_16x16x32_bf16(af_[mf], bf_[nf], acc[mf][nf], 0, 0, 0); \
        __builtin_amdgcn_s_setprio(0); }

    // prologue: chunks 0,1 in regs-in-flight
    LOADA(afA, 0) LOADB(bfA, 0)
    LOADA(afB, 1) LOADB(bfB, 1)

    // ---- gemm1: 64 K=32 chunks, register double-buffer, NO barriers ----
    #pragma unroll 4
    for (int s = 0; s < 64; s += 2) {
        MFMA16(afA, bfA);
        if (s < 62) { LOADA(afA, s + 2) LOADB(bfA, s + 2) }
        MFMA16(afB, bfB);
        if (s <= 60) { LOADA(afB, s + 3) LOADB(bfB, s + 3) }
    }

    // ---- ttile: acc -> bf16 [ru 0..31][pos 0..63]*16B at lds+0 ----
    // entry (ru,pos) holds T[pos][ru*8+e]; ru = wn*8 + nf*2 + (lr>>3), pos = mf*16+kg*4+r, e = lr&7
    {
        const int t0 = (wn * 8 + (lr >> 3)) * 1024 + (lr & 7) * 2;
        #pragma unroll
        for (int mf = 0; mf < 4; ++mf)
            #pragma unroll
            for (int nf = 0; nf < 4; ++nf)
                #pragma unroll
                for (int r = 0; r < 4; ++r)
                    *(ushort*)(lds + t0 + nf * 2048 + (mf * 16 + kg * 4 + r) * 16) =
                        (ushort)bf16r(acc[mf][nf][r]);
    }
    __syncthreads();

    // ---- gemm2: Y[64][512] = ttile @ Q^T, 2 mf-half passes; direct global stores ----
    const int a2base = kg * 1024 + lr * 16;
    int qoff[8];
    #pragma unroll
    for (int nf = 0; nf < 8; ++nf)
        qoff[nf] = ((wn >> 1) * 256 + (nf >> 2) * 128 + (wn & 1) * 64 + (nf & 3) * 16 + lr) * 64 + kg * 16;
    const int si = wn >> 1, ochalf = wn & 1;

    #pragma unroll
    for (int mh2 = 0; mh2 < 2; ++mh2) {
        f32x4 a2[2][8];
        #pragma unroll
        for (int u = 0; u < 2; ++u)
            #pragma unroll
            for (int j = 0; j < 8; ++j) a2[u][j] = (f32x4)0.f;
        #pragma unroll
        for (int ks = 0; ks < 8; ++ks) {
            short8 af2[2];
            af2[0] = *(const short8*)(lds + ks * 4096 + a2base + (mh2 * 2) * 256);
            af2[1] = *(const short8*)(lds + ks * 4096 + a2base + (mh2 * 2 + 1) * 256);
            #pragma unroll
            for (int nf = 0; nf < 8; ++nf) {
                const short8 bq = *(const short8*)(Qp4 + (size_t)ks * 32768 + qoff[nf]);
                a2[0][nf] = __builtin_amdgcn_mfma_f32_16x16x32_bf16(af2[0], bq, a2[0][nf], 0, 0, 0);
                a2[1][nf] = __builtin_amdgcn_mfma_f32_16x16x32_bf16(af2[1], bq, a2[1][nf], 0, 0, 0);
            }
        }
        // D-row pos = (2*mh2+u)*16 + kg*4 + r -> patchcol = 16u+4kg+r (rows pair mh2)
        // out h = vt*4 + mh2*2 + si ; w = 32u + 8kg + 2r + sj (sj: nf<4 -> 0, nf>=4 -> 1)
        const int r_out = vt * 4 + mh2 * 2 + si;
        float* ob = out + (size_t)n * 524288 + (size_t)r_out * 64;
        #pragma unroll
        for (int u = 0; u < 2; ++u)
            #pragma unroll
            for (int q = 0; q < 4; ++q) {
                const int oc = ochalf * 64 + q * 16 + lr;
                float* o2 = ob + (size_t)oc * 4096 + u * 32 + kg * 8;
                f32x4 v0 = { a2[u][q][0], a2[u][4 + q][0], a2[u][q][1], a2[u][4 + q][1] };
                f32x4 v1 = { a2[u][q][2], a2[u][4 + q][2], a2[u][q][3], a2[u][4 + q][3] };
                *(f32x4*)(o2) = v0;
                *(f32x4*)(o2 + 4) = v1;
            }
    }
}

extern "C" void kernel_launch(void* const* d_in, const int* in_sizes, int n_in,
                              void* d_out, int out_size, void* d_ws, size_t ws_size,
                              hipStream_t stream) {
    const float* x = (const float*)d_in[0];
    const float* Q = (const float*)d_in[1];
    const float* R = (const float*)d_in[2];
    float* out = (float*)d_out;

    char* ws = (char*)d_ws;
    char* Rp4 = ws;
    char* Qp4 = ws + QB_OFF;
    char* xph = ws + XPH_OFF;

    prep_kernel<<<2368, 256, 0, stream>>>(x, Q, R, Rp4, Qp4, xph);
    fused_kernel<<<512, 256, 32768, stream>>>(xph, Rp4, Qp4, out);
}

// Round 6
// 92.463 us; speedup vs baseline: 1.4067x; 1.4067x over previous
//
#include <hip/hip_runtime.h>
#include <hip/hip_bf16.h>

typedef __attribute__((ext_vector_type(8))) short short8;   // 8 bf16 (4 VGPRs)
typedef __attribute__((ext_vector_type(4))) float f32x4;
typedef unsigned int uint;
typedef __attribute__((ext_vector_type(4))) uint uint4v;    // align 16 -> dwordx4/b128

#define AS1 __attribute__((address_space(1)))
#define AS3 __attribute__((address_space(3)))

// ws: Rp4 [0,1MB) | Qp4 [1MB,1.25MB) | xph [1.25MB, +34.1MB)
#define QB_OFF  (1u << 20)
#define XPH_OFF (1310720u)
// xph byte addr: n*1115136 + row*16896 + col*256 + c*2   (row,col in 0..65, c in 0..127)
// Rp4: [s 0..63][cu 0..3][col 0..255]*16B ; holds R[col][k=s*32+cu*8+e]
//      (k-order: g=k>>7 window, c=k&127; f=c*16+g)
// Qp4: [ks 0..7][col 0..511][cu 0..3]*16B ; Q[col][ks*32+cu*8+e]

__device__ __forceinline__ uint bf16r(float f) {
    uint u = __float_as_uint(f);
    u += 0x7FFFu + ((u >> 16) & 1u);
    return u >> 16;
}
__device__ __forceinline__ uint pk2(float lo, float hi) {
    return bf16r(lo) | (bf16r(hi) << 16);
}

// ---------------- prep: NHWC-padded bf16 x, [cu][col] R slabs, Q K-slabs (unchanged, proven) ----------------
__global__ __launch_bounds__(256) void prep_kernel(
    const float* __restrict__ x, const float* __restrict__ Q, const float* __restrict__ R,
    char* __restrict__ Rp4, char* __restrict__ Qp4, char* __restrict__ xph)
{
    const int bid = blockIdx.x, tid = threadIdx.x;
    if (bid < 2048) {                       // transpose: n = bid>>6, h = bid&63
        __shared__ float xt[128 * 65];
        const int n = bid >> 6, h = bid & 63;
        {   // read x[n][c][h][w] coalesced, stage to LDS
            const int c = tid >> 1, half = tid & 1;
            const float4* src = (const float4*)(x + (((size_t)(n * 128 + c) * 64 + h) * 64 + half * 32));
            #pragma unroll
            for (int q = 0; q < 8; ++q) {
                float4 v = src[q];
                float* d = &xt[c * 65 + half * 32 + q * 4];
                d[0] = v.x; d[1] = v.y; d[2] = v.z; d[3] = v.w;
            }
        }
        __syncthreads();
        {   // write xph[n][h+1][w+1][c] (32 channels per thread)
            const int w = tid >> 2, cq = tid & 3;
            uint pw[16];
            #pragma unroll
            for (int m = 0; m < 16; ++m)
                pw[m] = pk2(xt[(cq * 32 + 2 * m) * 65 + w], xt[(cq * 32 + 2 * m + 1) * 65 + w]);
            char* dst = xph + (size_t)n * 1115136 + (size_t)(h + 1) * 16896 + (w + 1) * 256 + cq * 64;
            #pragma unroll
            for (int i = 0; i < 4; ++i) {
                uint4v q4 = { pw[4 * i], pw[4 * i + 1], pw[4 * i + 2], pw[4 * i + 3] };
                *(uint4v*)(dst + i * 16) = q4;
            }
        }
        if (tid < 32) {                      // col borders 0 and 65
            int side = tid >> 4, e = tid & 15;
            uint4v z = {0, 0, 0, 0};
            *(uint4v*)(xph + (size_t)n * 1115136 + (size_t)(h + 1) * 16896 + side * 65 * 256 + e * 16) = z;
        }
        if (h == 0) {                        // row borders 0 and 65
            uint4v z = {0, 0, 0, 0};
            #pragma unroll
            for (int it = 0; it < 9; ++it) {
                int idx = tid + it * 256;
                if (idx < 2112) {
                    int rr = (idx >= 1056) ? 65 : 0;
                    int jj = idx - (rr ? 1056 : 0);
                    int col = jj >> 4, e = jj & 15;
                    *(uint4v*)(xph + (size_t)n * 1115136 + (size_t)rr * 16896 + col * 256 + e * 16) = z;
                }
            }
        }
    } else if (bid < 2304) {                // R -> Rp4[s][cu][col] (linear dst)
        int g = (bid - 2048) * 256 + tid;   // 0..65535
        int s = g >> 10, rem = g & 1023;
        int cu = rem >> 8, col = rem & 255;
        // k = s*32 + cu*8 + e ; g_win = s>>2 ; c = (s&3)*32 + cu*8 + e ; f = c*16 + g_win
        const float* src = R + (size_t)col * 2048 + (((s & 3) * 32 + cu * 8) * 16 + (s >> 2));
        uint pw[4];
        #pragma unroll
        for (int m = 0; m < 4; ++m)
            pw[m] = pk2(src[(2 * m) * 16], src[(2 * m + 1) * 16]);
        uint4v q4 = { pw[0], pw[1], pw[2], pw[3] };
        *(uint4v*)(Rp4 + (size_t)g * 16) = q4;
    } else {                                 // Q -> Qp4[ks][col][cu] (linear dst)
        int g = (bid - 2304) * 256 + tid;   // 0..16383
        int ks = g >> 11, p = g & 2047;
        int col = p >> 2, cu = p & 3;
        const float4* s = (const float4*)(Q + (size_t)col * 256 + ks * 32 + cu * 8);
        float4 a = s[0], b = s[1];
        uint4v q4 = { pk2(a.x, a.y), pk2(a.z, a.w), pk2(b.x, b.y), pk2(b.z, b.w) };
        *(uint4v*)(Qp4 + (size_t)ks * 32768 + p * 16) = q4;
    }
}

// ---------------- fused: BM=128 x BN=256, 512 thr / 8 waves (2M x 4N), m201 skeleton ----------------
// 64 phases, one K=32 chunk each. 4-deep slab rotation: A 4x8KB [0,32K) | B 4x16KB [32K,96K).
// Phase t: {STAGE(t+3): 3 gll ; ds_read 8 frags of tile t} -> s_barrier -> lgkmcnt(0) ->
//          setprio(1) 16 MFMA setprio(0) -> s_waitcnt vmcnt(6) + s_barrier.
// Ledger: STAGE(t+1) was issued at phase t-2; at end-of-t the newer in-flight are
// STAGE(t+2):3 + STAGE(t+3):3 -> vmcnt(6) drains exactly t+1 (>= 2-phase latency cover,
// never 0 in the loop). ttile 64KB [0,64K) after gemm1; gemm2 barrier-free (global Q);
// direct 16B stores (R4-proven mapping).
__global__ __launch_bounds__(512, 2) void fused_kernel(
    const char* __restrict__ xph, const char* __restrict__ Rp4,
    const char* __restrict__ Qp4, float* __restrict__ out)
{
    extern __shared__ __align__(16) char lds[];

    const int blk = blockIdx.x;
    const int b = (blk & 7) * 32 + (blk >> 3);  // XCD-contiguous swizzle (256%8==0)
    const int n = b >> 3, vt = b & 7;           // vt: 4 ov-rows (8 xph rows) per block
    const int tid = threadIdx.x;
    const int wave = tid >> 6, lane = tid & 63;
    const int lr = lane & 15, kg = lane >> 4;
    const int wm = wave >> 2, wn = wave & 3;    // gemm1: rows wm*64.., rank cols wn*64..

    const char* xbase = xph + (size_t)n * 1115136;
    const int u16 = tid * 16;

    // A-stage per-thread: linear dest = tid*16 ; layout [cu=tid>>7][pos=tid&127]*16B
    const int xc = (8 * vt + 2 * ((tid >> 5) & 3)) * 16896 + (tid & 31) * 512 + (tid >> 7) * 16;

    // gemm1 fragment bases (both conflict-free: quarter-wave reads 256B contiguous)
    const int a0 = kg * 2048 + (wm * 64 + lr) * 16;   // + mf*256
    const int b0 = kg * 4096 + (wn * 64 + lr) * 16;   // + nf*256

#define STAGE(t_) { \
        __builtin_amdgcn_global_load_lds( \
            (const AS1 void*)(xbase + xc + ((t_) >> 4) * 16896 + (((t_) >> 2) & 3) * 256 + ((t_) & 3) * 64), \
            (AS3 void*)(lds + ((t_) & 3) * 8192 + u16), 16, 0, 0); \
        _Pragma("unroll") for (int q = 0; q < 2; ++q) \
            __builtin_amdgcn_global_load_lds( \
                (const AS1 void*)(Rp4 + (size_t)(t_) * 16384 + q * 8192 + u16), \
                (AS3 void*)(lds + 32768 + ((t_) & 3) * 16384 + q * 8192 + u16), 16, 0, 0); }

#define BAR1 { __builtin_amdgcn_sched_barrier(0); \
        asm volatile("s_barrier\n\ts_waitcnt lgkmcnt(0)" ::: "memory"); \
        __builtin_amdgcn_sched_barrier(0); }
#define BAR(Nstr) { __builtin_amdgcn_sched_barrier(0); \
        asm volatile("s_waitcnt vmcnt(" Nstr ") lgkmcnt(0)\n\ts_barrier" ::: "memory"); \
        __builtin_amdgcn_sched_barrier(0); }

    f32x4 acc[4][4];
    #pragma unroll
    for (int i = 0; i < 4; ++i)
        #pragma unroll
        for (int j = 0; j < 4; ++j) acc[i][j] = (f32x4)0.f;

    // prologue: tiles 0,1,2 in flight (9 loads); drain tile 0, keep 1,2
    STAGE(0) STAGE(1) STAGE(2)
    BAR("6")

    // ---- gemm1: 64 phases ----
    #pragma unroll
    for (int t = 0; t < 64; ++t) {
        if (t <= 60) STAGE(t + 3)
        const char* xs = lds + (t & 3) * 8192;
        const char* bs = lds + 32768 + (t & 3) * 16384;
        short8 af[4], bf[4];
        #pragma unroll
        for (int mf = 0; mf < 4; ++mf)
            af[mf] = *(const short8*)(xs + a0 + mf * 256);
        #pragma unroll
        for (int nf = 0; nf < 4; ++nf)
            bf[nf] = *(const short8*)(bs + b0 + nf * 256);
        BAR1
        __builtin_amdgcn_s_setprio(1);
        #pragma unroll
        for (int nf = 0; nf < 4; ++nf)
            #pragma unroll
            for (int mf = 0; mf < 4; ++mf)
                acc[mf][nf] = __builtin_amdgcn_mfma_f32_16x16x32_bf16(af[mf], bf[nf], acc[mf][nf], 0, 0, 0);
        __builtin_amdgcn_s_setprio(0);
        if (t <= 60)      { BAR("6") }
        else if (t == 61) { BAR("3") }
        else              { BAR("0") }
    }

    // ---- ttile: acc -> bf16 [ru 0..31][pos 0..127]*16B at lds+0 (all slabs dead) ----
    // entry (ru,pos) = T[pos][ru*8+e]; ru = wn*8+nf*2+(lr>>3), pos = wm*64+mf*16+kg*4+r, e = lr&7
    {
        const int t0 = (wn * 8 + (lr >> 3)) * 2048 + wm * 1024 + (lr & 7) * 2;
        #pragma unroll
        for (int mf = 0; mf < 4; ++mf)
            #pragma unroll
            for (int nf = 0; nf < 4; ++nf)
                #pragma unroll
                for (int r = 0; r < 4; ++r)
                    *(ushort*)(lds + t0 + nf * 4096 + (mf * 16 + kg * 4 + r) * 16) =
                        (ushort)bf16r(acc[mf][nf][r]);
    }
    __builtin_amdgcn_sched_barrier(0);
    asm volatile("s_waitcnt lgkmcnt(0)\n\ts_barrier" ::: "memory");
    __builtin_amdgcn_sched_barrier(0);

    // ---- gemm2: Y[128][512] = ttile @ Q^T ; global Q (L2-hot), barrier-free ----
    const int a2 = kg * 2048 + wm * 1024 + lr * 16;   // + ks*8192 + mf*256
    int qoff[8];
    #pragma unroll
    for (int nf = 0; nf < 8; ++nf)
        qoff[nf] = ((wn >> 1) * 256 + (nf >> 2) * 128 + (wn & 1) * 64 + (nf & 3) * 16 + lr) * 64 + kg * 16;
    const int si = wn >> 1, ochalf = wn & 1;

    f32x4 acc2[4][8];
    #pragma unroll
    for (int i = 0; i < 4; ++i)
        #pragma unroll
        for (int j = 0; j < 8; ++j) acc2[i][j] = (f32x4)0.f;
    #pragma unroll
    for (int ks = 0; ks < 8; ++ks) {
        short8 af2[4];
        #pragma unroll
        for (int mf = 0; mf < 4; ++mf)
            af2[mf] = *(const short8*)(lds + ks * 8192 + a2 + mf * 256);
        #pragma unroll
        for (int nf = 0; nf < 8; ++nf) {
            const short8 bq = *(const short8*)(Qp4 + (size_t)ks * 32768 + qoff[nf]);
            #pragma unroll
            for (int mf = 0; mf < 4; ++mf)
                acc2[mf][nf] = __builtin_amdgcn_mfma_f32_16x16x32_bf16(af2[mf], bq, acc2[mf][nf], 0, 0, 0);
        }
    }

    // ---- direct stores: lane's (mf,q) pair -> 2x dwordx4, w-contiguous (R4-proven map) ----
    // pos = wm*64+mf*16+kg*4+r -> ov-row = 4vt+2wm+(mf>>1), cl = (mf&1)*16+kg*4+r
    // h = 8vt+4wm+2*(mf>>1)+si ; w = (mf&1)*32+kg*8+2r+sj (sj=0 -> nf=q, sj=1 -> nf=4+q)
    #pragma unroll
    for (int mf = 0; mf < 4; ++mf) {
        const int h = 8 * vt + 4 * wm + 2 * (mf >> 1) + si;
        float* ob = out + (size_t)n * 524288 + (size_t)h * 64 + (mf & 1) * 32 + kg * 8;
        #pragma unroll
        for (int q = 0; q < 4; ++q) {
            const int oc = ochalf * 64 + q * 16 + lr;
            float* o2 = ob + (size_t)oc * 4096;
            f32x4 v0 = { acc2[mf][q][0], acc2[mf][4 + q][0], acc2[mf][q][1], acc2[mf][4 + q][1] };
            f32x4 v1 = { acc2[mf][q][2], acc2[mf][4 + q][2], acc2[mf][q][3], acc2[mf][4 + q][3] };
            *(f32x4*)(o2) = v0;
            *(f32x4*)(o2 + 4) = v1;
        }
    }
}

extern "C" void kernel_launch(void* const* d_in, const int* in_sizes, int n_in,
                              void* d_out, int out_size, void* d_ws, size_t ws_size,
                              hipStream_t stream) {
    const float* x = (const float*)d_in[0];
    const float* Q = (const float*)d_in[1];
    const float* R = (const float*)d_in[2];
    float* out = (float*)d_out;

    char* ws = (char*)d_ws;
    char* Rp4 = ws;
    char* Qp4 = ws + QB_OFF;
    char* xph = ws + XPH_OFF;

    prep_kernel<<<2368, 256, 0, stream>>>(x, Q, R, Rp4, Qp4, xph);
    fused_kernel<<<256, 512, 98304, stream>>>(xph, Rp4, Qp4, out);
}